// Round 1
// baseline (1383.451 us; speedup 1.0000x reference)
//
#include <hip/hip_runtime.h>
#include <math.h>

// Sinkhorn regularized transport, B=8, m=n=1024, fp32, 100 iterations.
//
// Persistent cooperative kernel:
//  - 256 blocks (1 per CU), 32 blocks per batch (batch = blockIdx & 7 so a
//    batch's blocks share an XCD under round-robin dispatch).
//  - Each block keeps its 32 rows of K = exp(-10*min(M,5)) resident in LDS
//    (stride 1028 floats: 16B-aligned rows, 4-bank skew per row).
//  - Per iteration: phase A accumulates partial y = K_rows^T * u_local via
//    atomicAdd into a per-batch global y buffer; ONE per-batch spin barrier;
//    phase B reads y, v = c/y, z_i = sum_j K[i][j] v_j, u_i = r/z_i (local).
//  - y is triple-buffered so the "zero the next buffer" store is separated
//    from readers by barrier t-1 and from writers by barrier t.

#define B_    8
#define N_    1024
#define G_    32          // blocks per batch
#define RPB   32          // rows per block
#define KSTR  1028        // LDS row stride (floats): 16B aligned, bank skew 4
#define NITER 100
#define TPB   256
#define LMB   10.0f
#define MAXD  5.0f

#define LDS_FLOATS (RPB * KSTR + N_ + RPB)

__device__ __forceinline__ void batch_barrier(int* cnt, int target) {
    __syncthreads();   // all waves' atomics drained (vmcnt(0) before s_barrier)
    if (threadIdx.x == 0) {
        __threadfence();                                   // release
        __hip_atomic_fetch_add(cnt, 1, __ATOMIC_RELAXED, __HIP_MEMORY_SCOPE_AGENT);
        while (__hip_atomic_load(cnt, __ATOMIC_RELAXED, __HIP_MEMORY_SCOPE_AGENT) < target) {
            __builtin_amdgcn_s_sleep(2);
        }
        __threadfence();                                   // acquire (invalidates L1)
    }
    __syncthreads();
}

__global__ void __launch_bounds__(TPB)
sinkhorn_kernel(const float* __restrict__ Mg,
                float* __restrict__ Pg,
                float* __restrict__ ybufs,   // [3][B_][N_]
                int* __restrict__ cnts)      // [B_ * 64] (256B-padded counters)
{
    extern __shared__ float lds[];
    float* Kl = lds;                    // RPB x KSTR
    float* vl = lds + RPB * KSTR;       // N_
    float* ul = vl + N_;                // RPB

    const int b    = blockIdx.x & (B_ - 1);
    const int g    = blockIdx.x >> 3;
    const int t    = threadIdx.x;
    const int row0 = g * RPB;
    const float r = 1.0f / (float)N_;
    const float c = 1.0f / (float)N_;

    // ---- stage K rows into LDS ----
    const float* Mb = Mg + ((size_t)b * N_ + row0) * N_;
    for (int i = 0; i < RPB; ++i) {
        float4 m4 = ((const float4*)(Mb + (size_t)i * N_))[t];
        float4 k4;
        k4.x = expf(-LMB * fminf(m4.x, MAXD));
        k4.y = expf(-LMB * fminf(m4.y, MAXD));
        k4.z = expf(-LMB * fminf(m4.z, MAXD));
        k4.w = expf(-LMB * fminf(m4.w, MAXD));
        *(float4*)&Kl[i * KSTR + 4 * t] = k4;
    }
    if (t < RPB) ul[t] = r;             // u = r initially
    __syncthreads();

    int* cnt = cnts + b * 64;

    for (int it = 0; it <= NITER; ++it) {
        float* yb = ybufs + ((size_t)(it % 3) * B_ + b) * N_;

        // ---- phase A: partial y_j += sum_{i in our rows} K[i][j] * u_i ----
        float4 a = make_float4(0.f, 0.f, 0.f, 0.f);
#pragma unroll
        for (int i = 0; i < RPB; ++i) {
            const float u  = ul[i];
            const float4 k4 = *(const float4*)&Kl[i * KSTR + 4 * t];
            a.x = fmaf(k4.x, u, a.x);
            a.y = fmaf(k4.y, u, a.y);
            a.z = fmaf(k4.z, u, a.z);
            a.w = fmaf(k4.w, u, a.w);
        }
        atomicAdd(&yb[4 * t + 0], a.x);
        atomicAdd(&yb[4 * t + 1], a.y);
        atomicAdd(&yb[4 * t + 2], a.z);
        atomicAdd(&yb[4 * t + 3], a.w);

        // zero next iteration's buffer (last touched at it-2; fenced by barriers)
        if (it < NITER && t < RPB) {
            float* yn = ybufs + ((size_t)((it + 1) % 3) * B_ + b) * N_;
            __hip_atomic_store(&yn[row0 + t], 0.0f, __ATOMIC_RELAXED,
                               __HIP_MEMORY_SCOPE_AGENT);
        }

        batch_barrier(cnt, (it + 1) * G_);

        // ---- v = c / y (each block computes full v; needed for its z rows) ----
        float4 y4 = ((const float4*)yb)[t];
        float4 v4 = make_float4(c / y4.x, c / y4.y, c / y4.z, c / y4.w);
        ((float4*)vl)[t] = v4;
        __syncthreads();

        if (it == NITER) break;         // vl holds final v

        // ---- phase B: z_i = sum_j K[i][j] v_j ; u_i = r / z_i ----
        const int rI = t >> 3;          // 0..31 (row within block)
        const int l  = t & 7;           // 0..7  (8 lanes per row, within a wave)
        float4 za = make_float4(0.f, 0.f, 0.f, 0.f);
#pragma unroll
        for (int k2 = 0; k2 < 32; ++k2) {
            const int j0 = 4 * l + 32 * k2;
            const float4 k4 = *(const float4*)&Kl[rI * KSTR + j0];
            const float4 vv = *(const float4*)&vl[j0];
            za.x = fmaf(k4.x, vv.x, za.x);
            za.y = fmaf(k4.y, vv.y, za.y);
            za.z = fmaf(k4.z, vv.z, za.z);
            za.w = fmaf(k4.w, vv.w, za.w);
        }
        float z = za.x + za.y + za.z + za.w;
        z += __shfl_xor(z, 1);
        z += __shfl_xor(z, 2);
        z += __shfl_xor(z, 4);
        if (l == 0) ul[rI] = r / z;
        __syncthreads();
    }

    // ---- epilogue: P[i][j] = u_i * K[i][j] * v_j ----
    float* Pb = Pg + ((size_t)b * N_ + row0) * N_;
    const float4 v4 = ((const float4*)vl)[t];
    for (int i = 0; i < RPB; ++i) {
        const float u  = ul[i];
        const float4 k4 = *(const float4*)&Kl[i * KSTR + 4 * t];
        float4 p4;
        p4.x = u * k4.x * v4.x;
        p4.y = u * k4.y * v4.y;
        p4.z = u * k4.z * v4.z;
        p4.w = u * k4.w * v4.w;
        ((float4*)(Pb + (size_t)i * N_))[t] = p4;
    }
}

extern "C" void kernel_launch(void* const* d_in, const int* in_sizes, int n_in,
                              void* d_out, int out_size, void* d_ws, size_t ws_size,
                              hipStream_t stream) {
    const float* M = (const float*)d_in[0];
    float* P = (float*)d_out;
    float* ybufs = (float*)d_ws;                                   // 3*8*1024 f32
    int* cnts = (int*)((char*)d_ws + (size_t)3 * B_ * N_ * sizeof(float));
    const size_t ctrl_bytes = (size_t)3 * B_ * N_ * sizeof(float)
                            + (size_t)B_ * 64 * sizeof(int);
    hipMemsetAsync(d_ws, 0, ctrl_bytes, stream);

    const size_t lds_bytes = (size_t)LDS_FLOATS * sizeof(float);
    // opt-in for >64KB dynamic LDS where required; ignore failure
    (void)hipFuncSetAttribute((const void*)sinkhorn_kernel,
                              hipFuncAttributeMaxDynamicSharedMemorySize,
                              (int)lds_bytes);

    void* args[] = { (void*)&M, (void*)&P, (void*)&ybufs, (void*)&cnts };
    hipError_t e = hipLaunchCooperativeKernel((void*)sinkhorn_kernel,
                                              dim3(B_ * G_), dim3(TPB),
                                              args, (unsigned)lds_bytes, stream);
    if (e != hipSuccess) {
        // fallback: plain launch; 1 block/CU * 256 blocks on a 256-CU chip is
        // naturally co-resident, which the spin barriers require
        sinkhorn_kernel<<<dim3(B_ * G_), dim3(TPB), lds_bytes, stream>>>(
            M, P, ybufs, cnts);
    }
}